// Round 4
// baseline (1404.360 us; speedup 1.0000x reference)
//
#include <hip/hip_runtime.h>
#include <hip/hip_bf16.h>
#include <hip/hip_fp16.h>

#define D 128

// ---------------- CSR build ----------------

__global__ void hist_kernel(const int* __restrict__ dst, int* __restrict__ counts, int E) {
    for (int e = blockIdx.x * blockDim.x + threadIdx.x; e < E; e += gridDim.x * blockDim.x)
        atomicAdd(&counts[dst[e]], 1);
}

__global__ __launch_bounds__(256) void scan_block_sums(const int* __restrict__ counts,
                                                       int* __restrict__ bsums, int N) {
    __shared__ int sdata[256];
    int t = threadIdx.x;
    int idx = blockIdx.x * 256 + t;
    sdata[t] = (idx < N) ? counts[idx] : 0;
    __syncthreads();
    for (int s = 128; s > 0; s >>= 1) {
        if (t < s) sdata[t] += sdata[t + s];
        __syncthreads();
    }
    if (t == 0) bsums[blockIdx.x] = sdata[0];
}

// single block, 1024 threads; nb <= 1024
__global__ __launch_bounds__(1024) void scan_single(int* __restrict__ bsums, int nb,
                                                    int* __restrict__ offsets, int N, int E) {
    __shared__ int sdata[1024];
    int t = threadIdx.x;
    int v = (t < nb) ? bsums[t] : 0;
    sdata[t] = v;
    __syncthreads();
    for (int off = 1; off < 1024; off <<= 1) {
        int u = (t >= off) ? sdata[t - off] : 0;
        __syncthreads();
        sdata[t] += u;
        __syncthreads();
    }
    if (t < nb) bsums[t] = sdata[t] - v;  // exclusive prefix of block sums
    if (t == 0) offsets[N] = E;
}

__global__ __launch_bounds__(256) void scan_final(const int* __restrict__ counts,
                                                  const int* __restrict__ bprefix,
                                                  int* __restrict__ offsets, int N) {
    __shared__ int sdata[256];
    int t = threadIdx.x;
    int idx = blockIdx.x * 256 + t;
    int c = (idx < N) ? counts[idx] : 0;
    sdata[t] = c;
    __syncthreads();
    for (int off = 1; off < 256; off <<= 1) {
        int u = (t >= off) ? sdata[t - off] : 0;
        __syncthreads();
        sdata[t] += u;
        __syncthreads();
    }
    if (idx < N) offsets[idx] = bprefix[blockIdx.x] + (sdata[t] - c);
}

__global__ void copy_cursor(const int* __restrict__ offsets, int* __restrict__ cursor, int N) {
    for (int i = blockIdx.x * blockDim.x + threadIdx.x; i < N; i += gridDim.x * blockDim.x)
        cursor[i] = offsets[i];
}

__global__ void fill_csr(const int* __restrict__ src, const int* __restrict__ dst,
                         int* __restrict__ cursor, int* __restrict__ csr, int E) {
    for (int e = blockIdx.x * blockDim.x + threadIdx.x; e < E; e += gridDim.x * blockDim.x) {
        int d = dst[e];
        int p = atomicAdd(&cursor[d], 1);
        csr[p] = src[e];
    }
}

// ---------------- fused dual GEMM: m = (bn(x))@W ; r = relu((bn(x))@Wr + br) ----------------
// m, r stored as fp16; optional BN scale/shift applied to x on load; x fp32 or fp16.

template <bool XHALF>
__global__ __launch_bounds__(256) void gemm_dual(const void* __restrict__ xv_,
                                                 const float* __restrict__ W,
                                                 const float* __restrict__ Wr,
                                                 const float* __restrict__ br,
                                                 __half* __restrict__ m,
                                                 __half* __restrict__ r,
                                                 const float* __restrict__ bn_sc,
                                                 const float* __restrict__ bn_sh,
                                                 int N) {
    __shared__ float4 xs[32][32];  // 32 rows x 128 cols
    int t = threadIdx.x;
    int i0 = blockIdx.x * 32;
    #pragma unroll
    for (int i = 0; i < 4; ++i) {
        int f = t + i * 256;  // 0..1023 slots (row, col4)
        int row = f >> 5, col = f & 31;
        int gr = i0 + row;
        float4 xv = make_float4(0.f, 0.f, 0.f, 0.f);
        if (gr < N) {
            if constexpr (XHALF) {
                uint2 u = ((const uint2*)xv_)[(size_t)gr * 32 + col];
                float2 f0 = __half22float2(*reinterpret_cast<__half2*>(&u.x));
                float2 f1 = __half22float2(*reinterpret_cast<__half2*>(&u.y));
                xv = make_float4(f0.x, f0.y, f1.x, f1.y);
            } else {
                xv = ((const float4*)xv_)[(size_t)gr * 32 + col];
            }
        }
        if (bn_sc) {
            float4 sc = *(const float4*)&bn_sc[col * 4];
            float4 sh = *(const float4*)&bn_sh[col * 4];
            xv.x = xv.x * sc.x + sh.x;
            xv.y = xv.y * sc.y + sh.y;
            xv.z = xv.z * sc.z + sh.z;
            xv.w = xv.w * sc.w + sh.w;
        }
        xs[row][col] = xv;
    }
    __syncthreads();

    int col = t & 127;
    int which = t >> 7;  // 0 -> m (W), 1 -> r (Wr)
    const float* Wsel = which ? Wr : W;

    float acc[32];
    #pragma unroll
    for (int rr = 0; rr < 32; ++rr) acc[rr] = 0.f;

    for (int k4 = 0; k4 < 32; ++k4) {
        int k = k4 * 4;
        float w0 = Wsel[(k + 0) * D + col];
        float w1 = Wsel[(k + 1) * D + col];
        float w2 = Wsel[(k + 2) * D + col];
        float w3 = Wsel[(k + 3) * D + col];
        #pragma unroll
        for (int rr = 0; rr < 32; ++rr) {
            float4 xv = xs[rr][k4];
            acc[rr] += xv.x * w0 + xv.y * w1 + xv.z * w2 + xv.w * w3;
        }
    }

    if (which == 0) {
        #pragma unroll
        for (int rr = 0; rr < 32; ++rr) {
            int gr = i0 + rr;
            if (gr < N) m[(size_t)gr * D + col] = __float2half(acc[rr]);
        }
    } else {
        float bb = br[col];
        #pragma unroll
        for (int rr = 0; rr < 32; ++rr) {
            int gr = i0 + rr;
            if (gr < N) r[(size_t)gr * D + col] = __float2half(fmaxf(acc[rr] + bb, 0.f));
        }
    }
}

// ---------------- per-node gather + combine + fused BN stats ----------------
// out = relu(sum_in m[src] + b) + r ; stats: 8-way replicated col sums/sumsq
// One node per 64-lane wave; two 32-lane halves gather different edges (8B/lane).
// NOTE: __shfl must execute with ALL 64 lanes active (wave-uniform path) —
// a shuffle whose source lane is exec-masked-off returns undefined data.

template <bool OHALF>
__global__ __launch_bounds__(256) void combine_kernel(const __half* __restrict__ m,
                                                      const int* __restrict__ csr,
                                                      const int* __restrict__ offsets,
                                                      const float* __restrict__ bias,
                                                      const __half* __restrict__ r,
                                                      void* __restrict__ out,
                                                      float* __restrict__ stats, int N) {
    __shared__ float sred[4][32][9];  // [wave][col4][sum0..3, sq0..3, pad]
    int t = threadIdx.x;
    int wave = t >> 6, lane = t & 63;
    int half = lane >> 5, l = lane & 31;
    int node = blockIdx.x * 4 + wave;

    float acc[4][4] = {};
    if (node < N) {
        int e0 = offsets[node], e1 = offsets[node + 1];
        const uint2* mp = (const uint2*)m;  // row = 32 x uint2 (8B = 4 fp16)
        for (int base = e0; base < e1; base += 64) {
            int idx = 0;
            if (base + lane < e1) idx = csr[base + lane];
            int navail = min(64, e1 - base);
            int npair = (navail + 1) >> 1;
            int i = 0;
            // __shfl OUTSIDE the guard: all 64 lanes active when it executes.
#define PAIR(slot, ii)                                                          \
            {                                                                   \
                int j = 2 * (ii) + half;                                        \
                int s = __shfl(idx, j);                                         \
                if (base + j < e1) {                                            \
                    uint2 pv = mp[(size_t)s * 32 + l];                          \
                    float2 f0 = __half22float2(*reinterpret_cast<__half2*>(&pv.x)); \
                    float2 f1 = __half22float2(*reinterpret_cast<__half2*>(&pv.y)); \
                    acc[slot][0] += f0.x; acc[slot][1] += f0.y;                 \
                    acc[slot][2] += f1.x; acc[slot][3] += f1.y;                 \
                }                                                               \
            }
            for (; i + 4 <= npair; i += 4) {
                PAIR(0, i) PAIR(1, i + 1) PAIR(2, i + 2) PAIR(3, i + 3)
            }
            for (; i < npair; ++i) { PAIR(0, i) }
#undef PAIR
        }
    }

    float o[4] = {0.f, 0.f, 0.f, 0.f};
    if (node < N) {
        float v[4];
        #pragma unroll
        for (int k = 0; k < 4; ++k) {
            float s = acc[0][k] + acc[1][k] + acc[2][k] + acc[3][k];
            s += __shfl_xor(s, 32);
            v[k] = s;
        }
        uint2 rv = ((const uint2*)r)[(size_t)node * 32 + l];
        float2 r0 = __half22float2(*reinterpret_cast<__half2*>(&rv.x));
        float2 r1 = __half22float2(*reinterpret_cast<__half2*>(&rv.y));
        float4 bv = *(const float4*)&bias[4 * l];
        o[0] = fmaxf(v[0] + bv.x, 0.f) + r0.x;
        o[1] = fmaxf(v[1] + bv.y, 0.f) + r0.y;
        o[2] = fmaxf(v[2] + bv.z, 0.f) + r1.x;
        o[3] = fmaxf(v[3] + bv.w, 0.f) + r1.y;
        if (half == 0) {
            if constexpr (OHALF) {
                __half2 h0 = __floats2half2_rn(o[0], o[1]);
                __half2 h1 = __floats2half2_rn(o[2], o[3]);
                uint2 u;
                u.x = *reinterpret_cast<uint*>(&h0);
                u.y = *reinterpret_cast<uint*>(&h1);
                ((uint2*)out)[(size_t)node * 32 + l] = u;
            } else {
                *(float4*)&((float*)out)[(size_t)node * D + 4 * l] =
                    make_float4(o[0], o[1], o[2], o[3]);
            }
        }
    }
    if (half == 0) {
        #pragma unroll
        for (int k = 0; k < 4; ++k) {
            sred[wave][l][k] = o[k];
            sred[wave][l][4 + k] = o[k] * o[k];
        }
    }
    __syncthreads();
    if (wave == 0) {
        int col4 = lane & 31, part = lane >> 5;  // part 0: sums, part 1: sqs
        float s0 = sred[0][col4][part * 4 + 0] + sred[1][col4][part * 4 + 0] +
                   sred[2][col4][part * 4 + 0] + sred[3][col4][part * 4 + 0];
        float s1 = sred[0][col4][part * 4 + 1] + sred[1][col4][part * 4 + 1] +
                   sred[2][col4][part * 4 + 1] + sred[3][col4][part * 4 + 1];
        float s2 = sred[0][col4][part * 4 + 2] + sred[1][col4][part * 4 + 2] +
                   sred[2][col4][part * 4 + 2] + sred[3][col4][part * 4 + 2];
        float s3 = sred[0][col4][part * 4 + 3] + sred[1][col4][part * 4 + 3] +
                   sred[2][col4][part * 4 + 3] + sred[3][col4][part * 4 + 3];
        float* bp = &stats[(part ? 1024 : 0) + (blockIdx.x & 7) * 128 + 4 * col4];
        atomicAdd(&bp[0], s0);
        atomicAdd(&bp[1], s1);
        atomicAdd(&bp[2], s2);
        atomicAdd(&bp[3], s3);
    }
}

// ---------------- BatchNorm finalize / apply ----------------

__global__ void bn_finalize(float* __restrict__ stats, const float* __restrict__ g,
                            const float* __restrict__ be, float invN) {
    int j = threadIdx.x;  // 128
    float s = 0.f, q = 0.f;
    #pragma unroll
    for (int c = 0; c < 8; ++c) {
        s += stats[c * 128 + j];
        q += stats[1024 + c * 128 + j];
    }
    float mu = s * invN;
    float var = q * invN - mu * mu;
    float sc = g[j] * rsqrtf(var + 1e-5f);
    stats[2048 + j] = sc;
    stats[2048 + 128 + j] = be[j] - mu * sc;
}

__global__ __launch_bounds__(256) void bn_apply(float* __restrict__ buf,
                                                const float* __restrict__ stats, int n4) {
    for (int i = blockIdx.x * blockDim.x + threadIdx.x; i < n4; i += gridDim.x * blockDim.x) {
        float4 v = ((const float4*)buf)[i];
        int c0 = (i * 4) & 127;
        float4 sc = *(const float4*)&stats[2048 + c0];
        float4 sh = *(const float4*)&stats[2048 + 128 + c0];
        v.x = v.x * sc.x + sh.x;
        v.y = v.y * sc.y + sh.y;
        v.z = v.z * sc.z + sh.z;
        v.w = v.w * sc.w + sh.w;
        ((float4*)buf)[i] = v;
    }
}

// ---------------- host ----------------

static inline char* align_up(char* p, size_t a) {
    return (char*)(((uintptr_t)p + (a - 1)) & ~(uintptr_t)(a - 1));
}

extern "C" void kernel_launch(void* const* d_in, const int* in_sizes, int n_in,
                              void* d_out, int out_size, void* d_ws, size_t ws_size,
                              hipStream_t stream) {
    const float* h   = (const float*)d_in[0];
    const int*   src = (const int*)d_in[1];
    const int*   dst = (const int*)d_in[2];
    const float* W0  = (const float*)d_in[3];
    const float* b0  = (const float*)d_in[4];
    const float* Wr0 = (const float*)d_in[5];
    const float* br0 = (const float*)d_in[6];
    const float* g0  = (const float*)d_in[7];
    const float* be0 = (const float*)d_in[8];
    const float* W1  = (const float*)d_in[9];
    const float* b1  = (const float*)d_in[10];
    const float* Wr1 = (const float*)d_in[11];
    const float* br1 = (const float*)d_in[12];
    const float* g1  = (const float*)d_in[13];
    const float* be1 = (const float*)d_in[14];

    const int N = in_sizes[0] / D;
    const int E = in_sizes[1];
    float* out = (float*)d_out;

    // workspace layout
    char* p = (char*)d_ws;
    __half* m_buf  = (__half*)p;              p += (size_t)N * D * sizeof(__half);
    p = align_up(p, 256);
    __half* x1_buf = (__half*)p;              p += (size_t)N * D * sizeof(__half);
    p = align_up(p, 256);
    __half* r_buf  = (__half*)p;              p += (size_t)N * D * sizeof(__half);
    p = align_up(p, 256);
    int* counts  = (int*)p;                   p += (size_t)N * sizeof(int);
    p = align_up(p, 256);
    int* offsets = (int*)p;                   p += (size_t)(N + 1) * sizeof(int);
    p = align_up(p, 256);
    int* cursor  = (int*)p;                   p += (size_t)N * sizeof(int);
    p = align_up(p, 256);
    int* bsums   = (int*)p;                   p += 1024 * sizeof(int);
    p = align_up(p, 256);
    int* csr     = (int*)p;                   p += (size_t)E * sizeof(int);
    p = align_up(p, 256);
    float* stats1 = (float*)p;                p += 2304 * sizeof(float);
    p = align_up(p, 256);
    float* stats2 = (float*)p;                p += 2304 * sizeof(float);
    (void)ws_size;

    const int nb = (N + 255) / 256;
    const float invN = 1.0f / (float)N;

    // ---- CSR build (shared across both layers) ----
    hipMemsetAsync(counts, 0, (size_t)N * sizeof(int), stream);
    hist_kernel<<<2048, 256, 0, stream>>>(dst, counts, E);
    scan_block_sums<<<nb, 256, 0, stream>>>(counts, bsums, N);
    scan_single<<<1, 1024, 0, stream>>>(bsums, nb, offsets, N, E);
    scan_final<<<nb, 256, 0, stream>>>(counts, bsums, offsets, N);
    copy_cursor<<<512, 256, 0, stream>>>(offsets, cursor, N);
    fill_csr<<<2048, 256, 0, stream>>>(src, dst, cursor, csr, E);

    const int gemm_grid = (N + 31) / 32;
    const int comb_grid = (N + 3) / 4;
    const int n4 = N * D / 4;

    // ---- layer 1: h (fp32) -> x1_buf (fp16, pre-BN; BN folded into layer-2 gemm load) ----
    gemm_dual<false><<<gemm_grid, 256, 0, stream>>>(h, W0, Wr0, br0, m_buf, r_buf,
                                                    nullptr, nullptr, N);
    hipMemsetAsync(stats1, 0, 2048 * sizeof(float), stream);
    combine_kernel<true><<<comb_grid, 256, 0, stream>>>(m_buf, csr, offsets, b0, r_buf,
                                                        x1_buf, stats1, N);
    bn_finalize<<<1, D, 0, stream>>>(stats1, g0, be0, invN);

    // ---- layer 2: bn(x1_buf fp16) -> out (fp32) ----
    gemm_dual<true><<<gemm_grid, 256, 0, stream>>>(x1_buf, W1, Wr1, br1, m_buf, r_buf,
                                                   stats1 + 2048, stats1 + 2048 + 128, N);
    hipMemsetAsync(stats2, 0, 2048 * sizeof(float), stream);
    combine_kernel<false><<<comb_grid, 256, 0, stream>>>(m_buf, csr, offsets, b1, r_buf,
                                                         out, stats2, N);
    bn_finalize<<<1, D, 0, stream>>>(stats2, g1, be1, invN);
    bn_apply<<<2048, 256, 0, stream>>>(out, stats2, n4);
}

// Round 5
// 995.209 us; speedup vs baseline: 1.4111x; 1.4111x over previous
//
#include <hip/hip_runtime.h>
#include <hip/hip_bf16.h>
#include <hip/hip_fp16.h>

#define D 128

// ---------------- CSR build ----------------

__global__ void hist_kernel(const int* __restrict__ dst, int* __restrict__ counts, int E) {
    for (int e = blockIdx.x * blockDim.x + threadIdx.x; e < E; e += gridDim.x * blockDim.x)
        atomicAdd(&counts[dst[e]], 1);
}

__global__ __launch_bounds__(256) void scan_block_sums(const int* __restrict__ counts,
                                                       int* __restrict__ bsums, int N) {
    __shared__ int sdata[256];
    int t = threadIdx.x;
    int idx = blockIdx.x * 256 + t;
    sdata[t] = (idx < N) ? counts[idx] : 0;
    __syncthreads();
    for (int s = 128; s > 0; s >>= 1) {
        if (t < s) sdata[t] += sdata[t + s];
        __syncthreads();
    }
    if (t == 0) bsums[blockIdx.x] = sdata[0];
}

// single block, 1024 threads; nb <= 1024
__global__ __launch_bounds__(1024) void scan_single(int* __restrict__ bsums, int nb,
                                                    int* __restrict__ offsets, int N, int E) {
    __shared__ int sdata[1024];
    int t = threadIdx.x;
    int v = (t < nb) ? bsums[t] : 0;
    sdata[t] = v;
    __syncthreads();
    for (int off = 1; off < 1024; off <<= 1) {
        int u = (t >= off) ? sdata[t - off] : 0;
        __syncthreads();
        sdata[t] += u;
        __syncthreads();
    }
    if (t < nb) bsums[t] = sdata[t] - v;  // exclusive prefix of block sums
    if (t == 0) offsets[N] = E;
}

__global__ __launch_bounds__(256) void scan_final(const int* __restrict__ counts,
                                                  const int* __restrict__ bprefix,
                                                  int* __restrict__ offsets, int N) {
    __shared__ int sdata[256];
    int t = threadIdx.x;
    int idx = blockIdx.x * 256 + t;
    int c = (idx < N) ? counts[idx] : 0;
    sdata[t] = c;
    __syncthreads();
    for (int off = 1; off < 256; off <<= 1) {
        int u = (t >= off) ? sdata[t - off] : 0;
        __syncthreads();
        sdata[t] += u;
        __syncthreads();
    }
    if (idx < N) offsets[idx] = bprefix[blockIdx.x] + (sdata[t] - c);
}

__global__ void copy_cursor(const int* __restrict__ offsets, int* __restrict__ cursor, int N) {
    for (int i = blockIdx.x * blockDim.x + threadIdx.x; i < N; i += gridDim.x * blockDim.x)
        cursor[i] = offsets[i];
}

__global__ void fill_csr(const int* __restrict__ src, const int* __restrict__ dst,
                         int* __restrict__ cursor, int* __restrict__ csr, int E) {
    for (int e = blockIdx.x * blockDim.x + threadIdx.x; e < E; e += gridDim.x * blockDim.x) {
        int d = dst[e];
        int p = atomicAdd(&cursor[d], 1);
        csr[p] = src[e];
    }
}

// ---------------- fused dual GEMM: m = (bn(x))@W ; r = relu((bn(x))@Wr + br) ----------------
// m, r stored as fp16; optional BN scale/shift applied to x on load; x fp32 or fp16.

template <bool XHALF>
__global__ __launch_bounds__(256) void gemm_dual(const void* __restrict__ xv_,
                                                 const float* __restrict__ W,
                                                 const float* __restrict__ Wr,
                                                 const float* __restrict__ br,
                                                 __half* __restrict__ m,
                                                 __half* __restrict__ r,
                                                 const float* __restrict__ bn_sc,
                                                 const float* __restrict__ bn_sh,
                                                 int N) {
    __shared__ float4 xs[32][32];  // 32 rows x 128 cols
    int t = threadIdx.x;
    int i0 = blockIdx.x * 32;
    #pragma unroll
    for (int i = 0; i < 4; ++i) {
        int f = t + i * 256;  // 0..1023 slots (row, col4)
        int row = f >> 5, col = f & 31;
        int gr = i0 + row;
        float4 xv = make_float4(0.f, 0.f, 0.f, 0.f);
        if (gr < N) {
            if constexpr (XHALF) {
                uint2 u = ((const uint2*)xv_)[(size_t)gr * 32 + col];
                float2 f0 = __half22float2(*reinterpret_cast<__half2*>(&u.x));
                float2 f1 = __half22float2(*reinterpret_cast<__half2*>(&u.y));
                xv = make_float4(f0.x, f0.y, f1.x, f1.y);
            } else {
                xv = ((const float4*)xv_)[(size_t)gr * 32 + col];
            }
        }
        if (bn_sc) {
            float4 sc = *(const float4*)&bn_sc[col * 4];
            float4 sh = *(const float4*)&bn_sh[col * 4];
            xv.x = xv.x * sc.x + sh.x;
            xv.y = xv.y * sc.y + sh.y;
            xv.z = xv.z * sc.z + sh.z;
            xv.w = xv.w * sc.w + sh.w;
        }
        xs[row][col] = xv;
    }
    __syncthreads();

    int col = t & 127;
    int which = t >> 7;  // 0 -> m (W), 1 -> r (Wr)
    const float* Wsel = which ? Wr : W;

    float acc[32];
    #pragma unroll
    for (int rr = 0; rr < 32; ++rr) acc[rr] = 0.f;

    for (int k4 = 0; k4 < 32; ++k4) {
        int k = k4 * 4;
        float w0 = Wsel[(k + 0) * D + col];
        float w1 = Wsel[(k + 1) * D + col];
        float w2 = Wsel[(k + 2) * D + col];
        float w3 = Wsel[(k + 3) * D + col];
        #pragma unroll
        for (int rr = 0; rr < 32; ++rr) {
            float4 xv = xs[rr][k4];
            acc[rr] += xv.x * w0 + xv.y * w1 + xv.z * w2 + xv.w * w3;
        }
    }

    if (which == 0) {
        #pragma unroll
        for (int rr = 0; rr < 32; ++rr) {
            int gr = i0 + rr;
            if (gr < N) m[(size_t)gr * D + col] = __float2half(acc[rr]);
        }
    } else {
        float bb = br[col];
        #pragma unroll
        for (int rr = 0; rr < 32; ++rr) {
            int gr = i0 + rr;
            if (gr < N) r[(size_t)gr * D + col] = __float2half(fmaxf(acc[rr] + bb, 0.f));
        }
    }
}

// ---------------- per-node gather + combine + fused BN stats ----------------
// out = relu(sum_in m[src] + b) + r ; stats: 8-way replicated col sums/sumsq
// Round-2 proven structure: one node per 64-lane wave, one dword (2 fp16 cols)
// per lane per edge row. Unroll 4 with NAMED scalar accumulators (no arrays ->
// no scratch de-registerization) + software-pipelined csr index loads.

template <bool OHALF>
__global__ __launch_bounds__(256) void combine_kernel(const __half* __restrict__ m,
                                                      const int* __restrict__ csr,
                                                      const int* __restrict__ offsets,
                                                      const float* __restrict__ bias,
                                                      const __half* __restrict__ r,
                                                      void* __restrict__ out,
                                                      float* __restrict__ stats, int N) {
    __shared__ float4 sred[4][64];
    int t = threadIdx.x;
    int wave = t >> 6, lane = t & 63;
    int node = blockIdx.x * 4 + wave;
    float v0 = 0.f, v1 = 0.f;
    if (node < N) {
        int e0 = offsets[node], e1 = offsets[node + 1];
        const uint* mp = (const uint*)m;  // row = 64 dwords (128 fp16)
        float a0 = 0.f, a1 = 0.f, b0 = 0.f, b1 = 0.f;
        float c0 = 0.f, c1 = 0.f, d0 = 0.f, d1 = 0.f;
        int e = e0;
        int s0 = 0, s1 = 0, s2 = 0, s3 = 0;
        if (e + 4 <= e1) { s0 = csr[e]; s1 = csr[e + 1]; s2 = csr[e + 2]; s3 = csr[e + 3]; }
        // steady state: issue next group's index loads before consuming current gathers
        for (; e + 8 <= e1; e += 4) {
            int n0 = csr[e + 4], n1 = csr[e + 5], n2 = csr[e + 6], n3 = csr[e + 7];
            uint p0 = mp[(size_t)s0 * 64 + lane];
            uint p1 = mp[(size_t)s1 * 64 + lane];
            uint p2 = mp[(size_t)s2 * 64 + lane];
            uint p3 = mp[(size_t)s3 * 64 + lane];
            float2 f0 = __half22float2(*reinterpret_cast<__half2*>(&p0));
            float2 f1 = __half22float2(*reinterpret_cast<__half2*>(&p1));
            float2 f2 = __half22float2(*reinterpret_cast<__half2*>(&p2));
            float2 f3 = __half22float2(*reinterpret_cast<__half2*>(&p3));
            a0 += f0.x; a1 += f0.y;
            b0 += f1.x; b1 += f1.y;
            c0 += f2.x; c1 += f2.y;
            d0 += f3.x; d1 += f3.y;
            s0 = n0; s1 = n1; s2 = n2; s3 = n3;
        }
        if (e + 4 <= e1) {  // drain the pipelined group
            uint p0 = mp[(size_t)s0 * 64 + lane];
            uint p1 = mp[(size_t)s1 * 64 + lane];
            uint p2 = mp[(size_t)s2 * 64 + lane];
            uint p3 = mp[(size_t)s3 * 64 + lane];
            float2 f0 = __half22float2(*reinterpret_cast<__half2*>(&p0));
            float2 f1 = __half22float2(*reinterpret_cast<__half2*>(&p1));
            float2 f2 = __half22float2(*reinterpret_cast<__half2*>(&p2));
            float2 f3 = __half22float2(*reinterpret_cast<__half2*>(&p3));
            a0 += f0.x; a1 += f0.y;
            b0 += f1.x; b1 += f1.y;
            c0 += f2.x; c1 += f2.y;
            d0 += f3.x; d1 += f3.y;
            e += 4;
        }
        for (; e < e1; ++e) {  // tail (<=3 edges)
            int s = csr[e];
            uint p = mp[(size_t)s * 64 + lane];
            float2 f = __half22float2(*reinterpret_cast<__half2*>(&p));
            a0 += f.x; a1 += f.y;
        }
        float sum0 = (a0 + b0) + (c0 + d0);
        float sum1 = (a1 + b1) + (c1 + d1);
        uint rv = ((const uint*)r)[(size_t)node * 64 + lane];
        float2 rf = __half22float2(*reinterpret_cast<__half2*>(&rv));
        float2 bv = *(const float2*)&bias[2 * lane];
        v0 = fmaxf(sum0 + bv.x, 0.f) + rf.x;
        v1 = fmaxf(sum1 + bv.y, 0.f) + rf.y;
        if constexpr (OHALF) {
            __half2 hv = __floats2half2_rn(v0, v1);
            ((uint*)out)[(size_t)node * 64 + lane] = *reinterpret_cast<uint*>(&hv);
        } else {
            *(float2*)&((float*)out)[(size_t)node * D + 2 * lane] = make_float2(v0, v1);
        }
    }
    sred[wave][lane] = make_float4(v0, v1, v0 * v0, v1 * v1);
    __syncthreads();
    if (wave == 0) {
        float4 q0 = sred[0][lane], q1 = sred[1][lane], q2 = sred[2][lane], q3 = sred[3][lane];
        int copy = blockIdx.x & 7;
        float* ss = &stats[copy * 128];
        float* sq = &stats[1024 + copy * 128];
        atomicAdd(&ss[2 * lane],     q0.x + q1.x + q2.x + q3.x);
        atomicAdd(&ss[2 * lane + 1], q0.y + q1.y + q2.y + q3.y);
        atomicAdd(&sq[2 * lane],     q0.z + q1.z + q2.z + q3.z);
        atomicAdd(&sq[2 * lane + 1], q0.w + q1.w + q2.w + q3.w);
    }
}

// ---------------- BatchNorm finalize / apply ----------------

__global__ void bn_finalize(float* __restrict__ stats, const float* __restrict__ g,
                            const float* __restrict__ be, float invN) {
    int j = threadIdx.x;  // 128
    float s = 0.f, q = 0.f;
    #pragma unroll
    for (int c = 0; c < 8; ++c) {
        s += stats[c * 128 + j];
        q += stats[1024 + c * 128 + j];
    }
    float mu = s * invN;
    float var = q * invN - mu * mu;
    float sc = g[j] * rsqrtf(var + 1e-5f);
    stats[2048 + j] = sc;
    stats[2048 + 128 + j] = be[j] - mu * sc;
}

__global__ __launch_bounds__(256) void bn_apply(float* __restrict__ buf,
                                                const float* __restrict__ stats, int n4) {
    for (int i = blockIdx.x * blockDim.x + threadIdx.x; i < n4; i += gridDim.x * blockDim.x) {
        float4 v = ((const float4*)buf)[i];
        int c0 = (i * 4) & 127;
        float4 sc = *(const float4*)&stats[2048 + c0];
        float4 sh = *(const float4*)&stats[2048 + 128 + c0];
        v.x = v.x * sc.x + sh.x;
        v.y = v.y * sc.y + sh.y;
        v.z = v.z * sc.z + sh.z;
        v.w = v.w * sc.w + sh.w;
        ((float4*)buf)[i] = v;
    }
}

// ---------------- host ----------------

static inline char* align_up(char* p, size_t a) {
    return (char*)(((uintptr_t)p + (a - 1)) & ~(uintptr_t)(a - 1));
}

extern "C" void kernel_launch(void* const* d_in, const int* in_sizes, int n_in,
                              void* d_out, int out_size, void* d_ws, size_t ws_size,
                              hipStream_t stream) {
    const float* h   = (const float*)d_in[0];
    const int*   src = (const int*)d_in[1];
    const int*   dst = (const int*)d_in[2];
    const float* W0  = (const float*)d_in[3];
    const float* b0  = (const float*)d_in[4];
    const float* Wr0 = (const float*)d_in[5];
    const float* br0 = (const float*)d_in[6];
    const float* g0  = (const float*)d_in[7];
    const float* be0 = (const float*)d_in[8];
    const float* W1  = (const float*)d_in[9];
    const float* b1  = (const float*)d_in[10];
    const float* Wr1 = (const float*)d_in[11];
    const float* br1 = (const float*)d_in[12];
    const float* g1  = (const float*)d_in[13];
    const float* be1 = (const float*)d_in[14];

    const int N = in_sizes[0] / D;
    const int E = in_sizes[1];
    float* out = (float*)d_out;

    // workspace layout
    char* p = (char*)d_ws;
    __half* m_buf  = (__half*)p;              p += (size_t)N * D * sizeof(__half);
    p = align_up(p, 256);
    __half* x1_buf = (__half*)p;              p += (size_t)N * D * sizeof(__half);
    p = align_up(p, 256);
    __half* r_buf  = (__half*)p;              p += (size_t)N * D * sizeof(__half);
    p = align_up(p, 256);
    int* counts  = (int*)p;                   p += (size_t)N * sizeof(int);
    p = align_up(p, 256);
    int* offsets = (int*)p;                   p += (size_t)(N + 1) * sizeof(int);
    p = align_up(p, 256);
    int* cursor  = (int*)p;                   p += (size_t)N * sizeof(int);
    p = align_up(p, 256);
    int* bsums   = (int*)p;                   p += 1024 * sizeof(int);
    p = align_up(p, 256);
    int* csr     = (int*)p;                   p += (size_t)E * sizeof(int);
    p = align_up(p, 256);
    float* stats1 = (float*)p;                p += 2304 * sizeof(float);
    p = align_up(p, 256);
    float* stats2 = (float*)p;                p += 2304 * sizeof(float);
    (void)ws_size;

    const int nb = (N + 255) / 256;
    const float invN = 1.0f / (float)N;

    // ---- CSR build (shared across both layers) ----
    hipMemsetAsync(counts, 0, (size_t)N * sizeof(int), stream);
    hist_kernel<<<2048, 256, 0, stream>>>(dst, counts, E);
    scan_block_sums<<<nb, 256, 0, stream>>>(counts, bsums, N);
    scan_single<<<1, 1024, 0, stream>>>(bsums, nb, offsets, N, E);
    scan_final<<<nb, 256, 0, stream>>>(counts, bsums, offsets, N);
    copy_cursor<<<512, 256, 0, stream>>>(offsets, cursor, N);
    fill_csr<<<2048, 256, 0, stream>>>(src, dst, cursor, csr, E);

    const int gemm_grid = (N + 31) / 32;
    const int comb_grid = (N + 3) / 4;
    const int n4 = N * D / 4;

    // ---- layer 1: h (fp32) -> x1_buf (fp16, pre-BN; BN folded into layer-2 gemm load) ----
    gemm_dual<false><<<gemm_grid, 256, 0, stream>>>(h, W0, Wr0, br0, m_buf, r_buf,
                                                    nullptr, nullptr, N);
    hipMemsetAsync(stats1, 0, 2048 * sizeof(float), stream);
    combine_kernel<true><<<comb_grid, 256, 0, stream>>>(m_buf, csr, offsets, b0, r_buf,
                                                        x1_buf, stats1, N);
    bn_finalize<<<1, D, 0, stream>>>(stats1, g0, be0, invN);

    // ---- layer 2: bn(x1_buf fp16) -> out (fp32) ----
    gemm_dual<true><<<gemm_grid, 256, 0, stream>>>(x1_buf, W1, Wr1, br1, m_buf, r_buf,
                                                   stats1 + 2048, stats1 + 2048 + 128, N);
    hipMemsetAsync(stats2, 0, 2048 * sizeof(float), stream);
    combine_kernel<false><<<comb_grid, 256, 0, stream>>>(m_buf, csr, offsets, b1, r_buf,
                                                         out, stats2, N);
    bn_finalize<<<1, D, 0, stream>>>(stats2, g1, be1, invN);
    bn_apply<<<2048, 256, 0, stream>>>(out, stats2, n4);
}

// Round 6
// 789.587 us; speedup vs baseline: 1.7786x; 1.2604x over previous
//
#include <hip/hip_runtime.h>
#include <hip/hip_bf16.h>
#include <hip/hip_fp16.h>

#define D 128

typedef _Float16 h8 __attribute__((ext_vector_type(8)));
typedef float f4 __attribute__((ext_vector_type(4)));

// ---------------- CSR build ----------------

__global__ void hist_kernel(const int* __restrict__ dst, int* __restrict__ counts, int E) {
    for (int e = blockIdx.x * blockDim.x + threadIdx.x; e < E; e += gridDim.x * blockDim.x)
        atomicAdd(&counts[dst[e]], 1);
}

__global__ __launch_bounds__(256) void scan_block_sums(const int* __restrict__ counts,
                                                       int* __restrict__ bsums, int N) {
    __shared__ int sdata[256];
    int t = threadIdx.x;
    int idx = blockIdx.x * 256 + t;
    sdata[t] = (idx < N) ? counts[idx] : 0;
    __syncthreads();
    for (int s = 128; s > 0; s >>= 1) {
        if (t < s) sdata[t] += sdata[t + s];
        __syncthreads();
    }
    if (t == 0) bsums[blockIdx.x] = sdata[0];
}

__global__ __launch_bounds__(1024) void scan_single(int* __restrict__ bsums, int nb,
                                                    int* __restrict__ offsets, int N, int E) {
    __shared__ int sdata[1024];
    int t = threadIdx.x;
    int v = (t < nb) ? bsums[t] : 0;
    sdata[t] = v;
    __syncthreads();
    for (int off = 1; off < 1024; off <<= 1) {
        int u = (t >= off) ? sdata[t - off] : 0;
        __syncthreads();
        sdata[t] += u;
        __syncthreads();
    }
    if (t < nb) bsums[t] = sdata[t] - v;
    if (t == 0) offsets[N] = E;
}

__global__ __launch_bounds__(256) void scan_final(const int* __restrict__ counts,
                                                  const int* __restrict__ bprefix,
                                                  int* __restrict__ offsets, int N) {
    __shared__ int sdata[256];
    int t = threadIdx.x;
    int idx = blockIdx.x * 256 + t;
    int c = (idx < N) ? counts[idx] : 0;
    sdata[t] = c;
    __syncthreads();
    for (int off = 1; off < 256; off <<= 1) {
        int u = (t >= off) ? sdata[t - off] : 0;
        __syncthreads();
        sdata[t] += u;
        __syncthreads();
    }
    if (idx < N) offsets[idx] = bprefix[blockIdx.x] + (sdata[t] - c);
}

__global__ void copy_cursor(const int* __restrict__ offsets, int* __restrict__ cursor, int N) {
    for (int i = blockIdx.x * blockDim.x + threadIdx.x; i < N; i += gridDim.x * blockDim.x)
        cursor[i] = offsets[i];
}

__global__ void fill_csr(const int* __restrict__ src, const int* __restrict__ dst,
                         int* __restrict__ cursor, int* __restrict__ csr, int E) {
    for (int e = blockIdx.x * blockDim.x + threadIdx.x; e < E; e += gridDim.x * blockDim.x) {
        int d = dst[e];
        int p = atomicAdd(&cursor[d], 1);
        csr[p] = src[e];
    }
}

// ---------------- weight pack (+ BN fold) ----------------
// Wp layout: [mat(2)][jt(8)][kt(4)][lane(64)][e(8)] fp16; frag for lane l:
// j = jt*16 + (l&15), k = kt*32 + (l>>4)*8 + e;  W' = sc[k]*W[k][j].
// cadd[j] = sum_k sh[k]*W[k][j]   (added to every m row in gemm epilogue)
// brp[j]  = br[j] + sum_k sh[k]*Wr[k][j]

__global__ __launch_bounds__(256) void pack_weights(const float* __restrict__ W,
                                                    const float* __restrict__ Wr,
                                                    const float* __restrict__ br_in,
                                                    const float* __restrict__ bn_sc,
                                                    const float* __restrict__ bn_sh,
                                                    __half* __restrict__ Wp,
                                                    float* __restrict__ cadd,
                                                    float* __restrict__ brp) {
    int t = threadIdx.x;
    for (int slot = t; slot < 4096; slot += 256) {
        int lane = slot & 63;
        int kt = (slot >> 6) & 3;
        int jt = (slot >> 8) & 7;
        int mat = slot >> 11;
        const float* Wsel = mat ? Wr : W;
        int j = jt * 16 + (lane & 15);
        int kb = kt * 32 + (lane >> 4) * 8;
        __half tmp[8];
        #pragma unroll
        for (int e = 0; e < 8; ++e) {
            int k = kb + e;
            float w = Wsel[k * D + j];
            if (bn_sc) w *= bn_sc[k];
            tmp[e] = __float2half(w);
        }
        *(uint4*)&Wp[(size_t)slot * 8] = *(const uint4*)tmp;
    }
    if (t < D) {
        float c = 0.f, bb = br_in[t];
        if (bn_sh) {
            for (int k = 0; k < D; ++k) {
                float sh = bn_sh[k];
                c += sh * W[k * D + t];
                bb += sh * Wr[k * D + t];
            }
        }
        cadd[t] = c;
        brp[t] = bb;
    }
}

// ---------------- MFMA dual GEMM: m = x@W' + cadd ; r = relu(x@Wr' + brp) ----------------
// 4 waves/block, 16 rows/wave, no LDS. A loaded row-major 16B/lane; B from packed Wp.

template <bool XHALF>
__global__ __launch_bounds__(256) void gemm_mfma(const void* __restrict__ x,
                                                 const __half* __restrict__ Wp,
                                                 const float* __restrict__ cadd,
                                                 const float* __restrict__ brp,
                                                 __half* __restrict__ m,
                                                 __half* __restrict__ r, int N) {
    int wv = threadIdx.x >> 6, lane = threadIdx.x & 63;
    int tilebase = blockIdx.x * 64 + wv * 16;
    int kgrp = lane >> 4;                 // 0..3
    int arow = tilebase + (lane & 15);
    bool rowok = arow < N;

    h8 a0v = 0, a1v = 0, a2v = 0, a3v = 0;
    if (rowok) {
        if constexpr (XHALF) {
            const __half* xp = (const __half*)x + (size_t)arow * D + kgrp * 8;
            a0v = *(const h8*)(xp + 0);
            a1v = *(const h8*)(xp + 32);
            a2v = *(const h8*)(xp + 64);
            a3v = *(const h8*)(xp + 96);
        } else {
            const float* xf = (const float*)x + (size_t)arow * D + kgrp * 8;
            #pragma unroll
            for (int kt = 0; kt < 4; ++kt) {
                f4 lo = *(const f4*)(xf + kt * 32);
                f4 hi = *(const f4*)(xf + kt * 32 + 4);
                h8 tv;
                tv[0] = (_Float16)lo[0]; tv[1] = (_Float16)lo[1];
                tv[2] = (_Float16)lo[2]; tv[3] = (_Float16)lo[3];
                tv[4] = (_Float16)hi[0]; tv[5] = (_Float16)hi[1];
                tv[6] = (_Float16)hi[2]; tv[7] = (_Float16)hi[3];
                if (kt == 0) a0v = tv; else if (kt == 1) a1v = tv;
                else if (kt == 2) a2v = tv; else a3v = tv;
            }
        }
    }

    f4 accm[8], accr[8];
    #pragma unroll
    for (int jt = 0; jt < 8; ++jt) { accm[jt] = 0; accr[jt] = 0; }

    const h8* wp = (const h8*)Wp;
    #pragma unroll
    for (int jt = 0; jt < 8; ++jt) {
        const h8* bm = wp + ((size_t)jt * 4) * 64 + lane;          // mat 0
        const h8* bw = wp + ((size_t)(8 + jt) * 4) * 64 + lane;    // mat 1
        accm[jt] = __builtin_amdgcn_mfma_f32_16x16x32_f16(a0v, bm[0 * 64], accm[jt], 0, 0, 0);
        accm[jt] = __builtin_amdgcn_mfma_f32_16x16x32_f16(a1v, bm[1 * 64], accm[jt], 0, 0, 0);
        accm[jt] = __builtin_amdgcn_mfma_f32_16x16x32_f16(a2v, bm[2 * 64], accm[jt], 0, 0, 0);
        accm[jt] = __builtin_amdgcn_mfma_f32_16x16x32_f16(a3v, bm[3 * 64], accm[jt], 0, 0, 0);
        accr[jt] = __builtin_amdgcn_mfma_f32_16x16x32_f16(a0v, bw[0 * 64], accr[jt], 0, 0, 0);
        accr[jt] = __builtin_amdgcn_mfma_f32_16x16x32_f16(a1v, bw[1 * 64], accr[jt], 0, 0, 0);
        accr[jt] = __builtin_amdgcn_mfma_f32_16x16x32_f16(a2v, bw[2 * 64], accr[jt], 0, 0, 0);
        accr[jt] = __builtin_amdgcn_mfma_f32_16x16x32_f16(a3v, bw[3 * 64], accr[jt], 0, 0, 0);
    }

    // D layout: col = jt*16 + (lane&15), row = tilebase + kgrp*4 + q
    int j0 = lane & 15;
    int orow0 = tilebase + kgrp * 4;
    #pragma unroll
    for (int jt = 0; jt < 8; ++jt) {
        int j = jt * 16 + j0;
        float cm = cadd[j];
        float bb = brp[j];
        #pragma unroll
        for (int q = 0; q < 4; ++q) {
            int row = orow0 + q;
            if (row < N) {
                m[(size_t)row * D + j] = __float2half(accm[jt][q] + cm);
                r[(size_t)row * D + j] = __float2half(fmaxf(accr[jt][q] + bb, 0.f));
            }
        }
    }
}

// ---------------- per-node gather + combine + fused BN stats ----------------
// Round-2 proven structure; 4 independent gathers/iter, named scalar accs,
// NO index prefetch (round-4/5 regressions came from extended live ranges).

template <bool OHALF>
__global__ __launch_bounds__(256) void combine_kernel(const __half* __restrict__ m,
                                                      const int* __restrict__ csr,
                                                      const int* __restrict__ offsets,
                                                      const float* __restrict__ bias,
                                                      const __half* __restrict__ r,
                                                      void* __restrict__ out,
                                                      float* __restrict__ stats, int N) {
    __shared__ float4 sred[4][64];
    int t = threadIdx.x;
    int wave = t >> 6, lane = t & 63;
    int node = blockIdx.x * 4 + wave;
    float v0 = 0.f, v1 = 0.f;
    if (node < N) {
        int e0 = offsets[node], e1 = offsets[node + 1];
        const uint* mp = (const uint*)m;  // row = 64 dwords (128 fp16)
        float a0 = 0.f, a1 = 0.f, b0 = 0.f, b1 = 0.f;
        float c0 = 0.f, c1 = 0.f, d0 = 0.f, d1 = 0.f;
        int e = e0;
        for (; e + 4 <= e1; e += 4) {
            int s0 = csr[e], s1 = csr[e + 1], s2 = csr[e + 2], s3 = csr[e + 3];
            uint p0 = mp[(size_t)s0 * 64 + lane];
            uint p1 = mp[(size_t)s1 * 64 + lane];
            uint p2 = mp[(size_t)s2 * 64 + lane];
            uint p3 = mp[(size_t)s3 * 64 + lane];
            float2 f0 = __half22float2(*reinterpret_cast<__half2*>(&p0));
            float2 f1 = __half22float2(*reinterpret_cast<__half2*>(&p1));
            float2 f2 = __half22float2(*reinterpret_cast<__half2*>(&p2));
            float2 f3 = __half22float2(*reinterpret_cast<__half2*>(&p3));
            a0 += f0.x; a1 += f0.y;
            b0 += f1.x; b1 += f1.y;
            c0 += f2.x; c1 += f2.y;
            d0 += f3.x; d1 += f3.y;
        }
        for (; e < e1; ++e) {
            int s = csr[e];
            uint p = mp[(size_t)s * 64 + lane];
            float2 f = __half22float2(*reinterpret_cast<__half2*>(&p));
            a0 += f.x; a1 += f.y;
        }
        float sum0 = (a0 + b0) + (c0 + d0);
        float sum1 = (a1 + b1) + (c1 + d1);
        uint rv = ((const uint*)r)[(size_t)node * 64 + lane];
        float2 rf = __half22float2(*reinterpret_cast<__half2*>(&rv));
        float2 bv = *(const float2*)&bias[2 * lane];
        v0 = fmaxf(sum0 + bv.x, 0.f) + rf.x;
        v1 = fmaxf(sum1 + bv.y, 0.f) + rf.y;
        if constexpr (OHALF) {
            __half2 hv = __floats2half2_rn(v0, v1);
            ((uint*)out)[(size_t)node * 64 + lane] = *reinterpret_cast<uint*>(&hv);
        } else {
            *(float2*)&((float*)out)[(size_t)node * D + 2 * lane] = make_float2(v0, v1);
        }
    }
    sred[wave][lane] = make_float4(v0, v1, v0 * v0, v1 * v1);
    __syncthreads();
    if (wave == 0) {
        float4 q0 = sred[0][lane], q1 = sred[1][lane], q2 = sred[2][lane], q3 = sred[3][lane];
        int copy = blockIdx.x & 7;
        float* ss = &stats[copy * 128];
        float* sq = &stats[1024 + copy * 128];
        atomicAdd(&ss[2 * lane],     q0.x + q1.x + q2.x + q3.x);
        atomicAdd(&ss[2 * lane + 1], q0.y + q1.y + q2.y + q3.y);
        atomicAdd(&sq[2 * lane],     q0.z + q1.z + q2.z + q3.z);
        atomicAdd(&sq[2 * lane + 1], q0.w + q1.w + q2.w + q3.w);
    }
}

// ---------------- BatchNorm finalize / apply ----------------

__global__ void bn_finalize(float* __restrict__ stats, const float* __restrict__ g,
                            const float* __restrict__ be, float invN) {
    int j = threadIdx.x;  // 128
    float s = 0.f, q = 0.f;
    #pragma unroll
    for (int c = 0; c < 8; ++c) {
        s += stats[c * 128 + j];
        q += stats[1024 + c * 128 + j];
    }
    float mu = s * invN;
    float var = q * invN - mu * mu;
    float sc = g[j] * rsqrtf(var + 1e-5f);
    stats[2048 + j] = sc;
    stats[2048 + 128 + j] = be[j] - mu * sc;
}

__global__ __launch_bounds__(256) void bn_apply(float* __restrict__ buf,
                                                const float* __restrict__ stats, int n4) {
    for (int i = blockIdx.x * blockDim.x + threadIdx.x; i < n4; i += gridDim.x * blockDim.x) {
        float4 v = ((const float4*)buf)[i];
        int c0 = (i * 4) & 127;
        float4 sc = *(const float4*)&stats[2048 + c0];
        float4 sh = *(const float4*)&stats[2048 + 128 + c0];
        v.x = v.x * sc.x + sh.x;
        v.y = v.y * sc.y + sh.y;
        v.z = v.z * sc.z + sh.z;
        v.w = v.w * sc.w + sh.w;
        ((float4*)buf)[i] = v;
    }
}

// ---------------- host ----------------

static inline char* align_up(char* p, size_t a) {
    return (char*)(((uintptr_t)p + (a - 1)) & ~(uintptr_t)(a - 1));
}

extern "C" void kernel_launch(void* const* d_in, const int* in_sizes, int n_in,
                              void* d_out, int out_size, void* d_ws, size_t ws_size,
                              hipStream_t stream) {
    const float* h   = (const float*)d_in[0];
    const int*   src = (const int*)d_in[1];
    const int*   dst = (const int*)d_in[2];
    const float* W0  = (const float*)d_in[3];
    const float* b0  = (const float*)d_in[4];
    const float* Wr0 = (const float*)d_in[5];
    const float* br0 = (const float*)d_in[6];
    const float* g0  = (const float*)d_in[7];
    const float* be0 = (const float*)d_in[8];
    const float* W1  = (const float*)d_in[9];
    const float* b1  = (const float*)d_in[10];
    const float* Wr1 = (const float*)d_in[11];
    const float* br1 = (const float*)d_in[12];
    const float* g1  = (const float*)d_in[13];
    const float* be1 = (const float*)d_in[14];

    const int N = in_sizes[0] / D;
    const int E = in_sizes[1];
    float* out = (float*)d_out;

    // workspace layout
    char* p = (char*)d_ws;
    __half* m_buf  = (__half*)p;              p += (size_t)N * D * sizeof(__half);
    p = align_up(p, 256);
    __half* x1_buf = (__half*)p;              p += (size_t)N * D * sizeof(__half);
    p = align_up(p, 256);
    __half* r_buf  = (__half*)p;              p += (size_t)N * D * sizeof(__half);
    p = align_up(p, 256);
    int* counts  = (int*)p;                   p += (size_t)N * sizeof(int);
    p = align_up(p, 256);
    int* offsets = (int*)p;                   p += (size_t)(N + 1) * sizeof(int);
    p = align_up(p, 256);
    int* cursor  = (int*)p;                   p += (size_t)N * sizeof(int);
    p = align_up(p, 256);
    int* bsums   = (int*)p;                   p += 1024 * sizeof(int);
    p = align_up(p, 256);
    int* csr     = (int*)p;                   p += (size_t)E * sizeof(int);
    p = align_up(p, 256);
    float* stats1 = (float*)p;                p += 2304 * sizeof(float);
    p = align_up(p, 256);
    float* stats2 = (float*)p;                p += 2304 * sizeof(float);
    p = align_up(p, 256);
    __half* Wp0 = (__half*)p;                 p += 32768 * sizeof(__half);
    p = align_up(p, 256);
    __half* Wp1 = (__half*)p;                 p += 32768 * sizeof(__half);
    p = align_up(p, 256);
    float* cadd0 = (float*)p;                 p += D * sizeof(float);
    float* brp0  = (float*)p;                 p += D * sizeof(float);
    float* cadd1 = (float*)p;                 p += D * sizeof(float);
    float* brp1  = (float*)p;                 p += D * sizeof(float);
    (void)ws_size;

    const int nb = (N + 255) / 256;
    const float invN = 1.0f / (float)N;

    // ---- CSR build (shared across both layers) ----
    hipMemsetAsync(counts, 0, (size_t)N * sizeof(int), stream);
    hist_kernel<<<2048, 256, 0, stream>>>(dst, counts, E);
    scan_block_sums<<<nb, 256, 0, stream>>>(counts, bsums, N);
    scan_single<<<1, 1024, 0, stream>>>(bsums, nb, offsets, N, E);
    scan_final<<<nb, 256, 0, stream>>>(counts, bsums, offsets, N);
    copy_cursor<<<512, 256, 0, stream>>>(offsets, cursor, N);
    fill_csr<<<2048, 256, 0, stream>>>(src, dst, cursor, csr, E);

    const int gemm_grid = (N + 63) / 64;
    const int comb_grid = (N + 3) / 4;
    const int n4 = N * D / 4;

    // ---- layer 1: h (fp32) -> x1_buf (fp16 raw; its BN folded into layer-2 weights) ----
    pack_weights<<<1, 256, 0, stream>>>(W0, Wr0, br0, nullptr, nullptr, Wp0, cadd0, brp0);
    gemm_mfma<false><<<gemm_grid, 256, 0, stream>>>(h, Wp0, cadd0, brp0, m_buf, r_buf, N);
    hipMemsetAsync(stats1, 0, 2048 * sizeof(float), stream);
    combine_kernel<true><<<comb_grid, 256, 0, stream>>>(m_buf, csr, offsets, b0, r_buf,
                                                        x1_buf, stats1, N);
    bn_finalize<<<1, D, 0, stream>>>(stats1, g0, be0, invN);

    // ---- layer 2: x1_buf (fp16 raw) -> out (fp32); BN1 folded into Wp1/cadd1/brp1 ----
    pack_weights<<<1, 256, 0, stream>>>(W1, Wr1, br1, stats1 + 2048, stats1 + 2048 + 128,
                                        Wp1, cadd1, brp1);
    gemm_mfma<true><<<gemm_grid, 256, 0, stream>>>(x1_buf, Wp1, cadd1, brp1, m_buf, r_buf, N);
    hipMemsetAsync(stats2, 0, 2048 * sizeof(float), stream);
    combine_kernel<false><<<comb_grid, 256, 0, stream>>>(m_buf, csr, offsets, b1, r_buf,
                                                         out, stats2, N);
    bn_finalize<<<1, D, 0, stream>>>(stats2, g1, be1, invN);
    bn_apply<<<2048, 256, 0, stream>>>(out, stats2, n4);
}